// Round 2
// baseline (355.791 us; speedup 1.0000x reference)
//
#include <hip/hip_runtime.h>
#include <math.h>

// Problem constants (match reference)
#define ALPHA     1.0f
#define BETA      0.001f
#define GAMMA     0.1f
#define THRESH    0.5f
#define LN2       0.69314718055994530942f

constexpr int B = 256, C = 2, H = 192, W = 256;
constexpr int HW   = H * W;          // 49152
constexpr int HW4  = HW / 4;         // 12288 float4 per (b,c) slab
constexpr long long NTOT = (long long)B * C * H * W;  // 25165824
constexpr int N4   = (int)(NTOT / 4);                  // 6291456

constexpr int BCE_BLOCKS   = 2048;   // 8 blocks/CU exact fill (32 waves/CU)
constexpr int PAIRS        = 12;     // 2048*256*12 == N4 exactly
constexpr int BATCH        = 6;      // loads kept in flight per batch
constexpr int DENSE_BLOCKS = 1024;
constexpr int FUSED_GRID   = DENSE_BLOCKS + BCE_BLOCKS;  // 3072

// ws layout (bytes):
//   [0      .. 8192 )  float pbx[2048]   bce partial sums
//   [8192   .. 16384)  float pby[2048]   cuts partial sums
//   [16384  .. 20480)  float pd [1024]   dense partial sums
//   [20480  .. 20484)  unsigned counter  (memset to 0 each launch)
constexpr int WS_PBX = 0;
constexpr int WS_PBY = 2048;
constexpr int WS_PD  = 4096;
constexpr int WS_CNT = 5120;  // in floats/uints (byte offset 20480)

// Native Clang vector type — __builtin_nontemporal_load rejects HIP's float4.
typedef float vfloat4 __attribute__((ext_vector_type(4)));

// Hardware v_log_f32 (log2) * ln2, ~1 ulp.
// LOG_CLAMP fmax dropped: inputs ∈ [1e-4, 1-1e-4] → log ∈ [-9.22, 0],
// the -100 clamp is provably never active — bit-identical removal.
__device__ __forceinline__ float fast_log(float x) {
    return __builtin_amdgcn_logf(x) * LN2;
}

__device__ __forceinline__ vfloat4 nt_load4(const vfloat4* p) {
    return __builtin_nontemporal_load(p);
}

__device__ __forceinline__ float wave_reduce(float v) {
#pragma unroll
    for (int off = 32; off > 0; off >>= 1)
        v += __shfl_down(v, off, 64);
    return v;
}

// ---- R9: single-dispatch fused kernel ----
// R8 profile: top-5 dispatches are all harness poison-fills (59.7 µs @ 6.73
// TB/s); our fused kernel is ≤59.5 µs (absent from top-5). The remaining
// structural overhead we own is the finalize dispatch + its launch gap.
// Fold it in via the deterministic last-block-done pattern:
//   - each block stores partials with agent-scope relaxed atomic stores
//   - one ACQ_REL agent fetch_add on a ws counter per block (release chain)
//   - the block seeing old == FUSED_GRID-1 has happens-before over all
//     partials (acquire emits cross-XCD buffer_inv) and runs the exact
//     finalize reduction loop — fixed order, bit-identical, no spinning.
__global__ __launch_bounds__(256, 8) void fused_kernel(
        const vfloat4* __restrict__ p4,
        const vfloat4* __restrict__ t4,
        const float*   __restrict__ in,
        float*  __restrict__ ws,
        float*  __restrict__ out) {

    float* pbx = ws + WS_PBX;
    float* pby = ws + WS_PBY;
    float* pd  = ws + WS_PD;
    unsigned* cnt = (unsigned*)(ws + WS_CNT);

    if (blockIdx.x < DENSE_BLOCKS) {
        // ---- dense penalty, segmented scan (R6 structure, chunked) ----
        // Hits in rows [1..190] of channel 1; consecutive hits (i,j) add
        // 1/(j-i)^3. Column split into 4 row-segments (4 waves/block),
        // merged via the associative (first, last, sum) monoid in LDS.
        const int lane = threadIdx.x & 63;
        const int seg  = threadIdx.x >> 6;            // 0..3, rows [seg*48, +48)
        const int j    = blockIdx.x * 64 + lane;      // column id, 0..65535
        const int b    = j >> 8;                      // W == 256
        const int w    = j & 255;
        const float* col = in + ((b * 2 + 1) * H) * W + w;  // channel 1
        const int segbase = seg * 48;

        int   first = -1, last = -1;
        float sum = 0.0f;
#pragma unroll
        for (int kc = 0; kc < 48; kc += 12) {
            float v[12];
#pragma unroll
            for (int k = 0; k < 12; ++k)
                v[k] = col[(segbase + kc + k) * W];
#pragma unroll
            for (int k = 0; k < 12; ++k) {
                const int i = segbase + kc + k;
                const bool m = (v[k] > THRESH) && (i != 0) && (i != 191);
                if (m) {
                    if (last >= 0) {
                        const float d = (float)(i - last);
                        sum += __builtin_amdgcn_rcpf(d * d * d);
                    } else {
                        first = i;
                    }
                    last = i;
                }
            }
        }

        __shared__ int   sfirst[256];
        __shared__ int   slast[256];
        __shared__ float ssum[256];
        sfirst[threadIdx.x] = first;
        slast[threadIdx.x]  = last;
        ssum[threadIdx.x]   = sum;
        __syncthreads();

        if (threadIdx.x < 64) {  // wave 0 merges the 4 segments of its column
            int   mlast = -1;
            float msum  = 0.0f;
#pragma unroll
            for (int s = 0; s < 4; ++s) {
                const int idx = s * 64 + threadIdx.x;
                const int f = sfirst[idx];
                if (f >= 0) {
                    if (mlast >= 0) {
                        const float d = (float)(f - mlast);
                        msum += __builtin_amdgcn_rcpf(d * d * d);
                    }
                    msum += ssum[idx];
                    mlast = slast[idx];
                }
            }
            float r = wave_reduce(msum);
            if (threadIdx.x == 0)
                __hip_atomic_store(&pd[blockIdx.x], r,
                                   __ATOMIC_RELAXED, __HIP_MEMORY_SCOPE_AGENT);
        }
    } else {
        // ---- BCE sum + channel-0 count(>0.5) — R6/R7.5 loop unchanged ----
        // Batches of 6 pairs (12 nt loads issued back-to-back, 48 VGPRs of
        // data) under the 64-VGPR budget, so the allocator keeps them in
        // flight. R4 evidence: concurrency-limited; every added-concurrency
        // step has paid so far.
        const int bid  = blockIdx.x - DENSE_BLOCKS;
        const int base = bid * (256 * PAIRS) + threadIdx.x;

        float bce  = 0.0f;
        float cuts = 0.0f;

#pragma unroll
        for (int kb = 0; kb < PAIRS; kb += BATCH) {
            vfloat4 p[BATCH], t[BATCH];
#pragma unroll
            for (int u = 0; u < BATCH; ++u) {
                p[u] = nt_load4(&p4[base + (kb + u) * 256]);
                t[u] = nt_load4(&t4[base + (kb + u) * 256]);
            }
#pragma unroll
            for (int u = 0; u < BATCH; ++u) {
                const int f = base + (kb + u) * 256;
                const int c = (f / HW4) & 1;   // channel of this float4
#pragma unroll
                for (int e = 0; e < 4; ++e) {
                    const float pv = p[u][e];
                    const float tv = t[u][e];
                    const float lp = fast_log(pv);
                    const float lm = fast_log(1.0f - pv);
                    bce += lm + tv * (lp - lm);   // == t*lp + (1-t)*lm
                    if (c == 0)
                        cuts += (pv > THRESH ? 1.0f : 0.0f);
                }
            }
        }

        __shared__ float sb[4], sc[4];
        float rb = wave_reduce(bce);
        float rc = wave_reduce(cuts);
        const int lane = threadIdx.x & 63;
        const int wid  = threadIdx.x >> 6;
        if (lane == 0) { sb[wid] = rb; sc[wid] = rc; }
        __syncthreads();
        if (threadIdx.x == 0) {
            __hip_atomic_store(&pbx[bid], sb[0] + sb[1] + sb[2] + sb[3],
                               __ATOMIC_RELAXED, __HIP_MEMORY_SCOPE_AGENT);
            __hip_atomic_store(&pby[bid], sc[0] + sc[1] + sc[2] + sc[3],
                               __ATOMIC_RELAXED, __HIP_MEMORY_SCOPE_AGENT);
        }
    }

    // ---- last-block-done final reduction (replaces finalize_kernel) ----
    __shared__ bool lastflag;
    __syncthreads();
    if (threadIdx.x == 0) {
        unsigned old = __hip_atomic_fetch_add(cnt, 1u,
                           __ATOMIC_ACQ_REL, __HIP_MEMORY_SCOPE_AGENT);
        lastflag = (old == (unsigned)(FUSED_GRID - 1));
    }
    __syncthreads();
    if (!lastflag) return;

    // This block is last: all partials are visible (release chain through
    // the counter RMWs; the acquire invalidates stale cross-XCD lines).
    // Same reduction order as the old finalize_kernel → bit-identical out.
    float bsum = 0.0f, csum = 0.0f, dsum = 0.0f;
    for (int i = threadIdx.x; i < BCE_BLOCKS; i += 256) {
        bsum += __hip_atomic_load(&pbx[i], __ATOMIC_RELAXED,
                                  __HIP_MEMORY_SCOPE_AGENT);
        csum += __hip_atomic_load(&pby[i], __ATOMIC_RELAXED,
                                  __HIP_MEMORY_SCOPE_AGENT);
    }
    for (int i = threadIdx.x; i < DENSE_BLOCKS; i += 256)
        dsum += __hip_atomic_load(&pd[i], __ATOMIC_RELAXED,
                                  __HIP_MEMORY_SCOPE_AGENT);

    __shared__ float fb[4], fc[4], fd[4];
    float rb = wave_reduce(bsum);
    float rc = wave_reduce(csum);
    float rd = wave_reduce(dsum);
    const int lane = threadIdx.x & 63;
    const int wid  = threadIdx.x >> 6;
    if (lane == 0) { fb[wid] = rb; fc[wid] = rc; fd[wid] = rd; }
    __syncthreads();
    if (threadIdx.x == 0) {
        const float bce_sum   = fb[0] + fb[1] + fb[2] + fb[3];
        const float cuts_sum  = fc[0] + fc[1] + fc[2] + fc[3];
        const float dense_sum = fd[0] + fd[1] + fd[2] + fd[3];
        const float bce = -bce_sum / (float)NTOT;
        out[0] = ALPHA * bce + BETA * cuts_sum + GAMMA * dense_sum;
    }
}

extern "C" void kernel_launch(void* const* d_in, const int* in_sizes, int n_in,
                              void* d_out, int out_size, void* d_ws, size_t ws_size,
                              hipStream_t stream) {
    const float* inputs  = (const float*)d_in[0];
    const float* targets = (const float*)d_in[1];
    float* out = (float*)d_out;
    float* ws  = (float*)d_ws;

    // Zero the completion counter (ws is poisoned by the harness each
    // iteration). 4-byte memset node — capture-legal, cheaper than the
    // finalize dispatch it replaces.
    hipMemsetAsync((char*)d_ws + WS_CNT * sizeof(float), 0, sizeof(unsigned),
                   stream);

    fused_kernel<<<FUSED_GRID, 256, 0, stream>>>(
        (const vfloat4*)inputs, (const vfloat4*)targets, inputs, ws, out);
}

// Round 3
// 205.547 us; speedup vs baseline: 1.7309x; 1.7309x over previous
//
#include <hip/hip_runtime.h>
#include <math.h>

// Problem constants (match reference)
#define ALPHA     1.0f
#define BETA      0.001f
#define GAMMA     0.1f
#define THRESH    0.5f
#define LOG_CLAMP -100.0f
#define LN2       0.69314718055994530942f

constexpr int B = 256, C = 2, H = 192, W = 256;
constexpr int HW   = H * W;          // 49152
constexpr int HW4  = HW / 4;         // 12288 float4 per (b,c) slab
constexpr long long NTOT = (long long)B * C * H * W;  // 25165824
constexpr int N4   = (int)(NTOT / 4);                  // 6291456

constexpr int BCE_BLOCKS   = 2048;   // 8 blocks/CU exact fill (32 waves/CU)
constexpr int PAIRS        = 12;     // 2048*256*12 == N4 exactly
constexpr int BATCH        = 6;      // loads kept in flight per batch
constexpr int DENSE_BLOCKS = 1024;
constexpr int FUSED_GRID   = DENSE_BLOCKS + BCE_BLOCKS;  // 3072

// Native Clang vector type — __builtin_nontemporal_load rejects HIP's float4.
typedef float vfloat4 __attribute__((ext_vector_type(4)));

// Hardware v_log_f32 (log2) * ln2, ~1 ulp — threshold is 6.7e3 absolute.
__device__ __forceinline__ float fast_log(float x) {
    return fmaxf(__builtin_amdgcn_logf(x) * LN2, LOG_CLAMP);
}

__device__ __forceinline__ vfloat4 nt_load4(const vfloat4* p) {
    return __builtin_nontemporal_load(p);
}

__device__ __forceinline__ float wave_reduce(float v) {
#pragma unroll
    for (int off = 32; off > 0; off >>= 1)
        v += __shfl_down(v, off, 64);
    return v;
}

// ---- R10: exact revert to the proven R8 two-dispatch structure ----
// R9 post-mortem: folding finalize into this kernel (last-block-done,
// agent-scope ACQ_REL RMW + unified CFG tail) flipped the register
// allocator: VGPR_Count 64-class -> 32, the 6-pair batch (48 data VGPRs)
// could no longer be live, loads serialized, kernel went latency-bound at
// 613 GB/s / 202 us. The golden BCE loop is allocator-sensitive (same
// lesson as R7); the dispatch boundary protects its codegen. Do NOT couple
// anything to this kernel.
__global__ __launch_bounds__(256, 8) void fused_kernel(
        const vfloat4* __restrict__ p4,
        const vfloat4* __restrict__ t4,
        const float*   __restrict__ in,
        float2* __restrict__ part_bce,
        float*  __restrict__ part_dense) {

    if (blockIdx.x < DENSE_BLOCKS) {
        // ---- dense penalty, segmented scan (R6 structure, chunked) ----
        // Hits in rows [1..190] of channel 1; consecutive hits (i,j) add
        // 1/(j-i)^3. Column split into 4 row-segments (4 waves/block),
        // merged via the associative (first, last, sum) monoid in LDS.
        const int lane = threadIdx.x & 63;
        const int seg  = threadIdx.x >> 6;            // 0..3, rows [seg*48, +48)
        const int j    = blockIdx.x * 64 + lane;      // column id, 0..65535
        const int b    = j >> 8;                      // W == 256
        const int w    = j & 255;
        const float* col = in + ((b * 2 + 1) * H) * W + w;  // channel 1
        const int segbase = seg * 48;

        int   first = -1, last = -1;
        float sum = 0.0f;
#pragma unroll
        for (int kc = 0; kc < 48; kc += 12) {
            float v[12];
#pragma unroll
            for (int k = 0; k < 12; ++k)
                v[k] = col[(segbase + kc + k) * W];
#pragma unroll
            for (int k = 0; k < 12; ++k) {
                const int i = segbase + kc + k;
                const bool m = (v[k] > THRESH) && (i != 0) && (i != 191);
                if (m) {
                    if (last >= 0) {
                        const float d = (float)(i - last);
                        sum += __builtin_amdgcn_rcpf(d * d * d);
                    } else {
                        first = i;
                    }
                    last = i;
                }
            }
        }

        __shared__ int   sfirst[256];
        __shared__ int   slast[256];
        __shared__ float ssum[256];
        sfirst[threadIdx.x] = first;
        slast[threadIdx.x]  = last;
        ssum[threadIdx.x]   = sum;
        __syncthreads();

        if (threadIdx.x < 64) {  // wave 0 merges the 4 segments of its column
            int   mlast = -1;
            float msum  = 0.0f;
#pragma unroll
            for (int s = 0; s < 4; ++s) {
                const int idx = s * 64 + threadIdx.x;
                const int f = sfirst[idx];
                if (f >= 0) {
                    if (mlast >= 0) {
                        const float d = (float)(f - mlast);
                        msum += __builtin_amdgcn_rcpf(d * d * d);
                    }
                    msum += ssum[idx];
                    mlast = slast[idx];
                }
            }
            float r = wave_reduce(msum);
            if (threadIdx.x == 0)
                part_dense[blockIdx.x] = r;
        }
    } else {
        // ---- BCE sum + channel-0 count(>0.5) — R6/R7.5 loop unchanged ----
        // Batches of 6 pairs (12 nt loads issued back-to-back, 48 VGPRs of
        // data) under the 64-VGPR budget, so the allocator keeps them in
        // flight. R4 evidence: concurrency-limited; every added-concurrency
        // step has paid so far.
        const int bid  = blockIdx.x - DENSE_BLOCKS;
        const int base = bid * (256 * PAIRS) + threadIdx.x;

        float bce  = 0.0f;
        float cuts = 0.0f;

#pragma unroll
        for (int kb = 0; kb < PAIRS; kb += BATCH) {
            vfloat4 p[BATCH], t[BATCH];
#pragma unroll
            for (int u = 0; u < BATCH; ++u) {
                p[u] = nt_load4(&p4[base + (kb + u) * 256]);
                t[u] = nt_load4(&t4[base + (kb + u) * 256]);
            }
#pragma unroll
            for (int u = 0; u < BATCH; ++u) {
                const int f = base + (kb + u) * 256;
                const int c = (f / HW4) & 1;   // channel of this float4
#pragma unroll
                for (int e = 0; e < 4; ++e) {
                    const float pv = p[u][e];
                    const float tv = t[u][e];
                    const float lp = fast_log(pv);
                    const float lm = fast_log(1.0f - pv);
                    bce += lm + tv * (lp - lm);   // == t*lp + (1-t)*lm
                    if (c == 0)
                        cuts += (pv > THRESH ? 1.0f : 0.0f);
                }
            }
        }

        __shared__ float sb[4], sc[4];
        float rb = wave_reduce(bce);
        float rc = wave_reduce(cuts);
        const int lane = threadIdx.x & 63;
        const int wid  = threadIdx.x >> 6;
        if (lane == 0) { sb[wid] = rb; sc[wid] = rc; }
        __syncthreads();
        if (threadIdx.x == 0) {
            part_bce[bid] = make_float2(sb[0] + sb[1] + sb[2] + sb[3],
                                        sc[0] + sc[1] + sc[2] + sc[3]);
        }
    }
}

// ---- single-block reduction of all partials + final combine ----
__global__ __launch_bounds__(256) void finalize_kernel(
        const float2* __restrict__ part_bce,
        const float* __restrict__ part_dense,
        float* __restrict__ out) {
    float b = 0.0f, c = 0.0f, d = 0.0f;
    for (int i = threadIdx.x; i < BCE_BLOCKS; i += 256) {
        float2 v = part_bce[i];
        b += v.x;
        c += v.y;
    }
    for (int i = threadIdx.x; i < DENSE_BLOCKS; i += 256)
        d += part_dense[i];

    __shared__ float sb[4], sc[4], sd[4];
    float rb = wave_reduce(b);
    float rc = wave_reduce(c);
    float rd = wave_reduce(d);
    const int lane = threadIdx.x & 63;
    const int wid  = threadIdx.x >> 6;
    if (lane == 0) { sb[wid] = rb; sc[wid] = rc; sd[wid] = rd; }
    __syncthreads();
    if (threadIdx.x == 0) {
        const float bce_sum   = sb[0] + sb[1] + sb[2] + sb[3];
        const float cuts_sum  = sc[0] + sc[1] + sc[2] + sc[3];
        const float dense_sum = sd[0] + sd[1] + sd[2] + sd[3];
        const float bce = -bce_sum / (float)NTOT;
        out[0] = ALPHA * bce + BETA * cuts_sum + GAMMA * dense_sum;
    }
}

extern "C" void kernel_launch(void* const* d_in, const int* in_sizes, int n_in,
                              void* d_out, int out_size, void* d_ws, size_t ws_size,
                              hipStream_t stream) {
    const float* inputs  = (const float*)d_in[0];
    const float* targets = (const float*)d_in[1];
    float* out = (float*)d_out;

    // ws layout: [0 .. BCE_BLOCKS)  float2 bce partials
    //            then DENSE_BLOCKS float dense partials
    float2* part_bce   = (float2*)d_ws;
    float*  part_dense = (float*)d_ws + 2 * BCE_BLOCKS;

    fused_kernel<<<FUSED_GRID, 256, 0, stream>>>(
        (const vfloat4*)inputs, (const vfloat4*)targets, inputs,
        part_bce, part_dense);

    finalize_kernel<<<1, 256, 0, stream>>>(part_bce, part_dense, out);
}